// Round 1
// baseline (445.517 us; speedup 1.0000x reference)
//
#include <hip/hip_runtime.h>
#include <hip/hip_bf16.h>

#define BB 8
#define CC 64
#define HH 256
#define WW 256

__device__ __forceinline__ unsigned short f2bf(float f) {
    __hip_bfloat16 h = __float2bfloat16(f);   // RNE
    return *reinterpret_cast<unsigned short*>(&h);
}
__device__ __forceinline__ float bf2f(unsigned short u) {
    unsigned int v = ((unsigned int)u) << 16;
    float r;
    __builtin_memcpy(&r, &v, 4);
    return r;
}

// ---------------------------------------------------------------------------
// K1: fused 5x5 depthwise (pad 2) + 1x21 horizontal depthwise (pad 10)
// block = (strip of 8 rows) x (b,c).  512 threads: wave w -> row w, lane l -> cols 4l..4l+3
// writes attn2 as bf16 into ws1
// ---------------------------------------------------------------------------
__global__ __launch_bounds__(512) void k1_local_h(
        const float* __restrict__ x, const float* __restrict__ lw,
        const float* __restrict__ hw, unsigned short* __restrict__ a2out) {
    const int strip = blockIdx.x;          // 0..31
    const int bc    = blockIdx.y;          // 0..511
    const int c     = bc & (CC - 1);
    const int y0    = strip * 8;
    const int tid   = threadIdx.x;

    __shared__ float xs[12][264];          // rows y0-2..y0+9, cols idx = x+2 (0..259)
    __shared__ float a1[8][276];           // cols idx = x+10 (valid 10..265, zero pads)

    const float* xbase = x + (size_t)bc * HH * WW;
    for (int i = tid; i < 12 * 260; i += 512) {
        int rr = i / 260, ccx = i - rr * 260;
        int gy = y0 - 2 + rr, gx = ccx - 2;
        float v = 0.f;
        if (gy >= 0 && gy < HH && gx >= 0 && gx < WW) v = xbase[gy * WW + gx];
        xs[rr][ccx] = v;
    }
    for (int i = tid; i < 8 * 20; i += 512) {
        int rr = i / 20, jj = i - rr * 20;
        a1[rr][jj < 10 ? jj : (256 + jj)] = 0.f;
    }
    __syncthreads();

    const int r = tid >> 6;
    const int l = tid & 63;
    const float* lwc = lw + c * 25;        // block-uniform -> s_load

    float acc[4] = {0.f, 0.f, 0.f, 0.f};
    #pragma unroll
    for (int ky = 0; ky < 5; ++ky) {
        float row[8];
        #pragma unroll
        for (int j = 0; j < 8; ++j) row[j] = xs[r + ky][4 * l + j];
        #pragma unroll
        for (int kx = 0; kx < 5; ++kx) {
            float wv = lwc[ky * 5 + kx];
            #pragma unroll
            for (int j = 0; j < 4; ++j) acc[j] = fmaf(wv, row[j + kx], acc[j]);
        }
    }
    #pragma unroll
    for (int j = 0; j < 4; ++j) a1[r][10 + 4 * l + j] = acc[j];
    __syncthreads();

    float wnd[24];
    #pragma unroll
    for (int i = 0; i < 24; ++i) wnd[i] = a1[r][4 * l + i];   // 16B-aligned b128 reads
    float o[4] = {0.f, 0.f, 0.f, 0.f};
    const float* hwc = hw + c * 21;
    #pragma unroll
    for (int k = 0; k < 21; ++k) {
        float wv = hwc[k];
        #pragma unroll
        for (int j = 0; j < 4; ++j) o[j] = fmaf(wv, wnd[j + k], o[j]);
    }

    unsigned short* dst = a2out + (size_t)(bc * HH + y0 + r) * WW + 4 * l;
    ushort4 pk;
    pk.x = f2bf(o[0]); pk.y = f2bf(o[1]); pk.z = f2bf(o[2]); pk.w = f2bf(o[3]);
    *reinterpret_cast<ushort4*>(dst) = pk;
}

// ---------------------------------------------------------------------------
// K2a: 21x1 vertical depthwise (pad 10), scatter-into-registers.
// block = (strip of 32 rows) x (b,c).  256 threads, thread = one column.
// Each input row loaded exactly once; taps in SGPRs (block-uniform c).
// ---------------------------------------------------------------------------
__global__ __launch_bounds__(256) void k2a_v(
        const unsigned short* __restrict__ a2, const float* __restrict__ vw,
        unsigned short* __restrict__ a3) {
    const int strip = blockIdx.x;          // 0..7
    const int bc    = blockIdx.y;
    const int c     = bc & (CC - 1);
    const int y0    = strip * 32;
    const int xcol  = threadIdx.x;
    const float* vwc = vw + c * 21;        // s_load

    float acc[32];
    #pragma unroll
    for (int i = 0; i < 32; ++i) acc[i] = 0.f;

    const unsigned short* src = a2 + (size_t)bc * HH * WW + xcol;
    #pragma unroll
    for (int rr = 0; rr < 52; ++rr) {
        int gy = y0 + rr - 10;
        float v = 0.f;
        if (gy >= 0 && gy < HH) v = bf2f(src[gy * WW]);
        #pragma unroll
        for (int k = 0; k < 21; ++k) {
            int yl = rr - k;                       // compile-time prune
            if (yl >= 0 && yl < 32) acc[yl] = fmaf(vwc[k], v, acc[yl]);
        }
    }
    unsigned short* dst = a3 + (size_t)bc * HH * WW + (size_t)y0 * WW + xcol;
    #pragma unroll
    for (int y = 0; y < 32; ++y) dst[y * WW] = f2bf(acc[y]);
}

// ---------------------------------------------------------------------------
// K2b: 1x1 pointwise (64x64) + BN + sigmoid gate.
// block = one (b, y) row.  256 threads: wave w -> co 16w..16w+15, lane l -> px 4l..4l+3.
// attn3 row staged bf16 in LDS; pw weights via wave-uniform scalar loads.
// ---------------------------------------------------------------------------
__global__ __launch_bounds__(256) void k2b_pw(
        const unsigned short* __restrict__ a3, const float* __restrict__ x,
        const float* __restrict__ pw, const float* __restrict__ gamma,
        const float* __restrict__ beta, const float* __restrict__ mean,
        const float* __restrict__ var, float* __restrict__ out) {
    const int y   = blockIdx.x;
    const int b   = blockIdx.y;
    const int tid = threadIdx.x;

    __shared__ unsigned short a3s[64][256];   // 32 KB

    const unsigned short* abase = a3 + ((size_t)b * CC * HH + y) * WW;
    for (int i = tid; i < 64 * 64; i += 256) {
        int ci = i >> 6, q = (i & 63) << 2;
        ushort4 v = *reinterpret_cast<const ushort4*>(abase + (size_t)ci * HH * WW + q);
        *reinterpret_cast<ushort4*>(&a3s[ci][q]) = v;
    }
    __syncthreads();

    const int wu = __builtin_amdgcn_readfirstlane(tid >> 6);  // wave-uniform co group
    const int l  = tid & 63;

    float acc[64];
    #pragma unroll
    for (int i = 0; i < 64; ++i) acc[i] = 0.f;

    #pragma unroll 4
    for (int ci = 0; ci < 64; ++ci) {
        ushort4 raw = *reinterpret_cast<const ushort4*>(&a3s[ci][l << 2]);
        float p0 = bf2f(raw.x), p1 = bf2f(raw.y), p2 = bf2f(raw.z), p3 = bf2f(raw.w);
        #pragma unroll
        for (int j = 0; j < 16; ++j) {
            float wv = pw[(wu * 16 + j) * 64 + ci];   // scalar load
            acc[j * 4 + 0] = fmaf(wv, p0, acc[j * 4 + 0]);
            acc[j * 4 + 1] = fmaf(wv, p1, acc[j * 4 + 1]);
            acc[j * 4 + 2] = fmaf(wv, p2, acc[j * 4 + 2]);
            acc[j * 4 + 3] = fmaf(wv, p3, acc[j * 4 + 3]);
        }
    }

    #pragma unroll
    for (int j = 0; j < 16; ++j) {
        int co = wu * 16 + j;
        float inv = gamma[co] * rsqrtf(var[co] + 1e-5f);
        float sh  = beta[co] - mean[co] * inv;
        size_t off = (((size_t)b * CC + co) * HH + y) * WW + (l << 2);
        float4 xv = *reinterpret_cast<const float4*>(x + off);
        float4 r;
        float a;
        a = acc[j * 4 + 0] * inv + sh; r.x = xv.x / (1.f + __expf(-a));
        a = acc[j * 4 + 1] * inv + sh; r.y = xv.y / (1.f + __expf(-a));
        a = acc[j * 4 + 2] * inv + sh; r.z = xv.z / (1.f + __expf(-a));
        a = acc[j * 4 + 3] * inv + sh; r.w = xv.w / (1.f + __expf(-a));
        *reinterpret_cast<float4*>(out + off) = r;
    }
}

extern "C" void kernel_launch(void* const* d_in, const int* in_sizes, int n_in,
                              void* d_out, int out_size, void* d_ws, size_t ws_size,
                              hipStream_t stream) {
    const float* x     = (const float*)d_in[0];
    const float* lw    = (const float*)d_in[1];
    const float* hw    = (const float*)d_in[2];
    const float* vw    = (const float*)d_in[3];
    const float* pw    = (const float*)d_in[4];
    const float* gamma = (const float*)d_in[5];
    const float* beta  = (const float*)d_in[6];
    const float* mean  = (const float*)d_in[7];
    const float* var   = (const float*)d_in[8];
    float* out = (float*)d_out;

    // ws: attn2 (bf16) + attn3 (bf16) = 2 * 64 MiB = 128 MiB
    unsigned short* ws1 = (unsigned short*)d_ws;
    unsigned short* ws2 = ws1 + (size_t)BB * CC * HH * WW;

    k1_local_h<<<dim3(HH / 8, BB * CC), 512, 0, stream>>>(x, lw, hw, ws1);
    k2a_v<<<dim3(HH / 32, BB * CC), 256, 0, stream>>>(ws1, vw, ws2);
    k2b_pw<<<dim3(HH, BB), 256, 0, stream>>>(ws2, x, pw, gamma, beta, mean, var, out);
}